// Round 4
// baseline (84.566 us; speedup 1.0000x reference)
//
#include <hip/hip_runtime.h>
#include <hip/hip_bf16.h>

#define B_ROWS 4096
#define D_FEAT 512

typedef short s16x8 __attribute__((ext_vector_type(8)));
typedef float f32x4 __attribute__((ext_vector_type(4)));

__device__ inline float waveReduceSum(float v) {
#pragma unroll
    for (int off = 32; off > 0; off >>= 1) v += __shfl_xor(v, off);
    return v;
}

// ---- prep: fp32->bf16 convert + sqnorm(rounded) + ws init; blocks 0..15 also do focal+KD ----
__global__ __launch_bounds__(256) void prep_kernel(const float* __restrict__ feat,
                                                   const float* __restrict__ logits,
                                                   const int* __restrict__ labels,
                                                   const float* __restrict__ soft,
                                                   short* __restrict__ featbf,
                                                   float* __restrict__ sqn,
                                                   unsigned* __restrict__ posmax,
                                                   float* __restrict__ negminf,
                                                   float* __restrict__ fpart,
                                                   float* __restrict__ kpart) {
    const int bid = blockIdx.x, tid = threadIdx.x;
    const int wave = tid >> 6, lane = tid & 63;
    const int row = bid * 4 + wave;

    // convert 4 rows per block, one wave per row (8 elems/lane)
    const float* p = feat + (size_t)row * D_FEAT + lane * 8;
    float4 a = *(const float4*)p;
    float4 b = *(const float4*)(p + 4);
    float vals[8] = {a.x, a.y, a.z, a.w, b.x, b.y, b.z, b.w};
    short outv[8];
    float s = 0.f;
#pragma unroll
    for (int j = 0; j < 8; ++j) {
        __hip_bfloat16 h = __float2bfloat16(vals[j]);
        outv[j] = *(short*)&h;
        float xb = __bfloat162float(h);
        s = fmaf(xb, xb, s);
    }
    *(s16x8*)(featbf + (size_t)row * D_FEAT + lane * 8) = *(s16x8*)outv;
    s = waveReduceSum(s);
    if (lane == 0) sqn[row] = s;

    // init batch-hard accumulators (d^2 domain: neg fill = 1e12 = (1e6)^2)
    if (tid < 4) posmax[bid * 4 + tid] = 0u;
    else if (tid < 8) negminf[bid * 4 + tid - 4] = 1e12f;

    // focal + KD: blocks 0..15, one row per thread
    if (bid < 16) {
        int i = bid * 256 + tid;
        float l0 = logits[2 * i], l1 = logits[2 * i + 1];

        float m = fmaxf(l0, l1);
        float lse = m + logf(expf(l0 - m) + expf(l1 - m));
        float lp = (labels[i] ? l1 : l0) - lse;
        float ce = -lp;
        float pt = expf(lp);
        float om = 1.f - pt;
        float focal = om * om * ce;

        const float Tinv = 1.f / 3.f;
        float s0 = l0 * Tinv, s1 = l1 * Tinv;
        float ms = fmaxf(s0, s1);
        float lses = ms + logf(expf(s0 - ms) + expf(s1 - ms));
        float sl0 = s0 - lses, sl1 = s1 - lses;
        float t0 = logf(soft[2 * i] + 1e-8f) * Tinv;
        float t1 = logf(soft[2 * i + 1] + 1e-8f) * Tinv;
        float mt = fmaxf(t0, t1);
        float lset = mt + logf(expf(t0 - mt) + expf(t1 - mt));
        float tl0 = t0 - lset, tl1 = t1 - lset;
        float p0 = expf(tl0), p1 = expf(tl1);
        float kd = p0 * (tl0 - sl0) + p1 * (tl1 - sl1);

        float fs = waveReduceSum(focal);
        float ks = waveReduceSum(kd);
        __shared__ float sf[4], sk[4];
        if (lane == 0) { sf[wave] = fs; sk[wave] = ks; }
        __syncthreads();
        if (tid == 0) {
            fpart[bid] = sf[0] + sf[1] + sf[2] + sf[3];
            kpart[bid] = sk[0] + sk[1] + sk[2] + sk[3];
        }
    }
}

// ---- pairwise d^2 via bf16 MFMA, LDS-free (L2-direct fragments), symmetric jb>=ib ----
// 4 waves (2x2), wave tile 64x64 = 4x4 mfma_f32_16x16x32_bf16 frags.
// Each tile feeds BOTH row-side (over lo lanes) and col-side (over hi lanes) batch-hard
// reductions; atomics are idempotent max/min so diagonal-block overlap is harmless.
__global__ __launch_bounds__(256) void pairwise_sym_kernel(const short* __restrict__ featbf,
                                                           const float* __restrict__ sqn,
                                                           const int* __restrict__ labels,
                                                           unsigned* __restrict__ posmax,
                                                           unsigned* __restrict__ negmin) {
    // decode upper-triangle block index (ib <= jb < 32)
    int ib = 0, t = blockIdx.x;
    while (t >= 32 - ib) { t -= 32 - ib; ++ib; }
    const int jb = ib + t;

    const int tid = threadIdx.x;
    const int wid = tid >> 6, lane = tid & 63;
    const int wr = wid >> 1, wc = wid & 1;
    const int lo = lane & 15, hi = lane >> 4;

    const short* Abase = featbf + (size_t)(ib * 128 + wr * 64 + lo) * D_FEAT + hi * 8;
    const short* Bbase = featbf + (size_t)(jb * 128 + wc * 64 + lo) * D_FEAT + hi * 8;

    f32x4 acc[4][4];
#pragma unroll
    for (int m = 0; m < 4; ++m)
#pragma unroll
        for (int n = 0; n < 4; ++n)
            acc[m][n] = (f32x4){0.f, 0.f, 0.f, 0.f};

#pragma unroll 4
    for (int kk = 0; kk < D_FEAT / 32; ++kk) {
        s16x8 af[4], bfr[4];
#pragma unroll
        for (int m = 0; m < 4; ++m)
            af[m] = *(const s16x8*)(Abase + (size_t)m * 16 * D_FEAT + kk * 32);
#pragma unroll
        for (int n = 0; n < 4; ++n)
            bfr[n] = *(const s16x8*)(Bbase + (size_t)n * 16 * D_FEAT + kk * 32);
#pragma unroll
        for (int m = 0; m < 4; ++m)
#pragma unroll
            for (int n = 0; n < 4; ++n)
                acc[m][n] = __builtin_amdgcn_mfma_f32_16x16x32_bf16(af[m], bfr[n],
                                                                   acc[m][n], 0, 0, 0);
    }

    // ---- epilogue in d^2 domain ----
    // C/D layout (m89-verified): col = lane&15 (lo), row = hi*4 + reg
    int coln[4], labc[4];
    float sqc[4], pmc[4], nmc[4];
#pragma unroll
    for (int n = 0; n < 4; ++n) {
        coln[n] = jb * 128 + wc * 64 + n * 16 + lo;
        labc[n] = labels[coln[n]];
        sqc[n] = sqn[coln[n]];
        pmc[n] = 0.f;
        nmc[n] = 1e12f;
    }
#pragma unroll
    for (int m = 0; m < 4; ++m) {
#pragma unroll
        for (int r = 0; r < 4; ++r) {
            int row_g = ib * 128 + wr * 64 + m * 16 + hi * 4 + r;
            int labr = labels[row_g];
            float sqr = sqn[row_g];
            float pm = 0.f, nm = 1e12f;
#pragma unroll
            for (int n = 0; n < 4; ++n) {
                float d2 = fmaxf(sqr + fmaf(-2.f, acc[m][n][r], sqc[n]), 0.f);
                bool same = (labr == labc[n]);
                if (same) {
                    if (row_g != coln[n]) {
                        pm = fmaxf(pm, d2);
                        pmc[n] = fmaxf(pmc[n], d2);
                    }
                } else {
                    nm = fminf(nm, d2);
                    nmc[n] = fminf(nmc[n], d2);
                }
            }
            // row-side: reduce over the 16 lo lanes within each hi group
#pragma unroll
            for (int off = 1; off < 16; off <<= 1) {
                pm = fmaxf(pm, __shfl_xor(pm, off));
                nm = fminf(nm, __shfl_xor(nm, off));
            }
            if (lo == 0) {
                atomicMax(&posmax[row_g], __float_as_uint(pm));
                atomicMin(&negmin[row_g], __float_as_uint(nm));
            }
        }
    }
    // col-side: reduce over the 4 hi groups
#pragma unroll
    for (int n = 0; n < 4; ++n) {
        float pm = pmc[n], nm = nmc[n];
        pm = fmaxf(pm, __shfl_xor(pm, 16));
        pm = fmaxf(pm, __shfl_xor(pm, 32));
        nm = fminf(nm, __shfl_xor(nm, 16));
        nm = fminf(nm, __shfl_xor(nm, 32));
        if (hi == 0) {
            atomicMax(&posmax[coln[n]], __float_as_uint(pm));
            atomicMin(&negmin[coln[n]], __float_as_uint(nm));
        }
    }
}

// ---- final reduction + scalar combine (sqrt deferred to here; float32 outputs) ----
__global__ __launch_bounds__(256) void finalize_kernel(const unsigned* __restrict__ posmax,
                                                       const unsigned* __restrict__ negmin,
                                                       const float* __restrict__ fpart,
                                                       const float* __restrict__ kpart,
                                                       float* __restrict__ out) {
    int tid = threadIdx.x;
    float sum_pr = 0.f, sum_v = 0.f;
    for (int i = tid; i < B_ROWS; i += 256) {
        float p2 = __uint_as_float(posmax[i]);
        float n2 = __uint_as_float(negmin[i]);
        float v = (p2 > 0.f) ? 1.f : 0.f;
        sum_pr += fmaxf(sqrtf(p2) - sqrtf(n2) + 0.3f, 0.f) * v;
        sum_v += v;
    }
    sum_pr = waveReduceSum(sum_pr);
    sum_v = waveReduceSum(sum_v);
    __shared__ float sp[4], sv[4];
    int wave = tid >> 6, lane = tid & 63;
    if (lane == 0) { sp[wave] = sum_pr; sv[wave] = sum_v; }
    __syncthreads();
    if (tid == 0) {
        float spr = sp[0] + sp[1] + sp[2] + sp[3];
        float svv = sv[0] + sv[1] + sv[2] + sv[3];
        float fsum = 0.f, ksum = 0.f;
        for (int b = 0; b < 16; ++b) { fsum += fpart[b]; ksum += kpart[b]; }
        float focal = fsum / 4096.f;
        float kd = ksum / 4096.f * 9.f;  // * T^2
        float triplet = (svv > 0.f) ? spr / fmaxf(svv, 1.f) : 0.f;
        float total = focal + 0.5f * triplet + kd;
        out[0] = total;
        out[1] = focal;
        out[2] = triplet;
        out[3] = kd;
    }
}

extern "C" void kernel_launch(void* const* d_in, const int* in_sizes, int n_in,
                              void* d_out, int out_size, void* d_ws, size_t ws_size,
                              hipStream_t stream) {
    const float* logits = (const float*)d_in[0];
    const float* feat   = (const float*)d_in[1];
    const int*   labels = (const int*)d_in[2];
    const float* soft   = (const float*)d_in[3];

    char* ws = (char*)d_ws;
    unsigned* posmax = (unsigned*)ws;                    // 4096 u32 (d^2 bits)
    unsigned* negmin = (unsigned*)(ws + 16384);          // 4096 u32 (d^2 bits)
    float*    sqn    = (float*)(ws + 32768);             // 4096 f32
    float*    fpart  = (float*)(ws + 49152);             // 16 f32
    float*    kpart  = (float*)(ws + 49152 + 256);       // 16 f32
    short*    featbf = (short*)(ws + 65536);             // 4096*512 bf16 = 4 MB

    prep_kernel<<<1024, 256, 0, stream>>>(feat, logits, labels, soft, featbf, sqn,
                                          posmax, (float*)negmin, fpart, kpart);
    pairwise_sym_kernel<<<528, 256, 0, stream>>>(featbf, sqn, labels, posmax, negmin);
    finalize_kernel<<<1, 256, 0, stream>>>(posmax, negmin, fpart, kpart,
                                           (float*)d_out);
}

// Round 5
// 61.379 us; speedup vs baseline: 1.3778x; 1.3778x over previous
//
#include <hip/hip_runtime.h>
#include <hip/hip_bf16.h>

#define B_ROWS 4096
#define D_FEAT 512

typedef short s16x8 __attribute__((ext_vector_type(8)));
typedef float f32x4 __attribute__((ext_vector_type(4)));

#define GLOAD_LDS16(gsrc, ldst)                                                        \
    __builtin_amdgcn_global_load_lds(                                                  \
        (const __attribute__((address_space(1))) void*)(gsrc),                         \
        (__attribute__((address_space(3))) void*)(ldst), 16, 0, 0)

__device__ inline float waveReduceSum(float v) {
#pragma unroll
    for (int off = 32; off > 0; off >>= 1) v += __shfl_xor(v, off);
    return v;
}

// ---- prep: fp32->bf16 convert + sqnorm(rounded) + ws init; blocks 0..15 also do focal+KD ----
__global__ __launch_bounds__(256) void prep_kernel(const float* __restrict__ feat,
                                                   const float* __restrict__ logits,
                                                   const int* __restrict__ labels,
                                                   const float* __restrict__ soft,
                                                   short* __restrict__ featbf,
                                                   float* __restrict__ sqn,
                                                   unsigned* __restrict__ posmax,
                                                   float* __restrict__ negminf,
                                                   float* __restrict__ fpart,
                                                   float* __restrict__ kpart) {
    const int bid = blockIdx.x, tid = threadIdx.x;
    const int wave = tid >> 6, lane = tid & 63;
    const int row = bid * 4 + wave;

    // convert 4 rows per block, one wave per row (8 elems/lane)
    const float* p = feat + (size_t)row * D_FEAT + lane * 8;
    float4 a = *(const float4*)p;
    float4 b = *(const float4*)(p + 4);
    float vals[8] = {a.x, a.y, a.z, a.w, b.x, b.y, b.z, b.w};
    short outv[8];
    float s = 0.f;
#pragma unroll
    for (int j = 0; j < 8; ++j) {
        __hip_bfloat16 h = __float2bfloat16(vals[j]);
        outv[j] = *(short*)&h;
        float xb = __bfloat162float(h);
        s = fmaf(xb, xb, s);
    }
    *(s16x8*)(featbf + (size_t)row * D_FEAT + lane * 8) = *(s16x8*)outv;
    s = waveReduceSum(s);
    if (lane == 0) sqn[row] = s;

    // init batch-hard accumulators (d^2 domain: neg fill = 1e12 = (1e6)^2)
    if (tid < 4) posmax[bid * 4 + tid] = 0u;
    else if (tid < 8) negminf[bid * 4 + tid - 4] = 1e12f;

    // focal + KD: blocks 0..15, one row per thread
    if (bid < 16) {
        int i = bid * 256 + tid;
        float l0 = logits[2 * i], l1 = logits[2 * i + 1];

        float m = fmaxf(l0, l1);
        float lse = m + logf(expf(l0 - m) + expf(l1 - m));
        float lp = (labels[i] ? l1 : l0) - lse;
        float ce = -lp;
        float pt = expf(lp);
        float om = 1.f - pt;
        float focal = om * om * ce;

        const float Tinv = 1.f / 3.f;
        float s0 = l0 * Tinv, s1 = l1 * Tinv;
        float ms = fmaxf(s0, s1);
        float lses = ms + logf(expf(s0 - ms) + expf(s1 - ms));
        float sl0 = s0 - lses, sl1 = s1 - lses;
        float t0 = logf(soft[2 * i] + 1e-8f) * Tinv;
        float t1 = logf(soft[2 * i + 1] + 1e-8f) * Tinv;
        float mt = fmaxf(t0, t1);
        float lset = mt + logf(expf(t0 - mt) + expf(t1 - mt));
        float tl0 = t0 - lset, tl1 = t1 - lset;
        float p0 = expf(tl0), p1 = expf(tl1);
        float kd = p0 * (tl0 - sl0) + p1 * (tl1 - sl1);

        float fs = waveReduceSum(focal);
        float ks = waveReduceSum(kd);
        __shared__ float sf[4], sk[4];
        if (lane == 0) { sf[wave] = fs; sk[wave] = ks; }
        __syncthreads();
        if (tid == 0) {
            fpart[bid] = sf[0] + sf[1] + sf[2] + sf[3];
            kpart[bid] = sk[0] + sk[1] + sk[2] + sk[3];
        }
    }
}

// ---- pairwise d^2 via bf16 MFMA: 128x128 tile, BK=64, global_load_lds(16B) staging ----
// LDS layout: [row][64 bf16] = 128B rows, 8 chunks of 16B. Effective swizzle
// chunk' = chunk ^ (row&7): applied on the GLOBAL SOURCE address (linear LDS dest,
// rule #21) and identically on the ds_read side (involution). ds_read_b128 of a
// fragment (16 lo-rows, fixed hi) then spreads over 8 bank-groups = 2-way (free).
// 4 waves (2x2), wave tile 64x64 = 4x4 mfma_f32_16x16x32_bf16 frags, 2 k-slices/step.
__global__ __launch_bounds__(256) void pairwise_glds_kernel(const short* __restrict__ featbf,
                                                            const float* __restrict__ sqn,
                                                            const int* __restrict__ labels,
                                                            unsigned* __restrict__ posmax,
                                                            unsigned* __restrict__ negmin) {
    __shared__ short As[128 * 64];
    __shared__ short Bs[128 * 64];
    const int tid = threadIdx.x;
    const int jb = blockIdx.x, ib = blockIdx.y;
    const int wid = tid >> 6, lane = tid & 63;
    const int wr = wid >> 1, wc = wid & 1;
    const int lo = lane & 15, hi = lane >> 4;

    // staging: 16 segments of 1KB per tile; wave stages segments wid*4..wid*4+3.
    // lane covers (row = seg*8 + lane/8, chunk' = lane&7); source chunk = chunk'^(row&7).
    const short* Asrc[4];
    const short* Bsrc[4];
    short* Adst[4];
    short* Bdst[4];
#pragma unroll
    for (int q = 0; q < 4; ++q) {
        int seg = wid * 4 + q;
        int row = seg * 8 + (lane >> 3);
        int c = (lane & 7) ^ (row & 7);
        Asrc[q] = featbf + (size_t)(ib * 128 + row) * D_FEAT + c * 8;
        Bsrc[q] = featbf + (size_t)(jb * 128 + row) * D_FEAT + c * 8;
        Adst[q] = As + seg * 512;  // wave-uniform base; HW adds lane*16B
        Bdst[q] = Bs + seg * 512;
    }

    // fragment ds_read offsets (in shorts), swizzled with the same involution
    int aoff[2][4], boff[2][4];
#pragma unroll
    for (int ks = 0; ks < 2; ++ks) {
#pragma unroll
        for (int m = 0; m < 4; ++m) {
            int ar = wr * 64 + m * 16 + lo;
            aoff[ks][m] = ar * 64 + ((ks * 4 + hi) ^ (ar & 7)) * 8;
            int bc = wc * 64 + m * 16 + lo;
            boff[ks][m] = bc * 64 + ((ks * 4 + hi) ^ (bc & 7)) * 8;
        }
    }

    f32x4 acc[4][4];
#pragma unroll
    for (int m = 0; m < 4; ++m)
#pragma unroll
        for (int n = 0; n < 4; ++n)
            acc[m][n] = (f32x4){0.f, 0.f, 0.f, 0.f};

    for (int kk = 0; kk < D_FEAT / 64; ++kk) {
#pragma unroll
        for (int q = 0; q < 4; ++q) {
            GLOAD_LDS16(Asrc[q] + kk * 64, Adst[q]);
            GLOAD_LDS16(Bsrc[q] + kk * 64, Bdst[q]);
        }
        __syncthreads();  // vmcnt(0) drain + barrier: tile resident
#pragma unroll
        for (int ks = 0; ks < 2; ++ks) {
            s16x8 af[4], bfr[4];
#pragma unroll
            for (int m = 0; m < 4; ++m) af[m] = *(const s16x8*)(As + aoff[ks][m]);
#pragma unroll
            for (int n = 0; n < 4; ++n) bfr[n] = *(const s16x8*)(Bs + boff[ks][n]);
#pragma unroll
            for (int m = 0; m < 4; ++m)
#pragma unroll
                for (int n = 0; n < 4; ++n)
                    acc[m][n] = __builtin_amdgcn_mfma_f32_16x16x32_bf16(af[m], bfr[n],
                                                                       acc[m][n], 0, 0, 0);
        }
        __syncthreads();  // reads done before next-step overwrite
    }

    // ---- epilogue in d^2 domain (C/D layout m89: col = lo, row = hi*4 + reg) ----
    int coln[4], labc[4];
    float sqc[4];
#pragma unroll
    for (int n = 0; n < 4; ++n) {
        coln[n] = jb * 128 + wc * 64 + n * 16 + lo;
        labc[n] = labels[coln[n]];
        sqc[n] = sqn[coln[n]];
    }
#pragma unroll
    for (int m = 0; m < 4; ++m) {
#pragma unroll
        for (int r = 0; r < 4; ++r) {
            int row_g = ib * 128 + wr * 64 + m * 16 + hi * 4 + r;
            int labr = labels[row_g];
            float sqr = sqn[row_g];
            float pm = 0.f, nm = 1e12f;
#pragma unroll
            for (int n = 0; n < 4; ++n) {
                float d2 = fmaxf(sqr + fmaf(-2.f, acc[m][n][r], sqc[n]), 0.f);
                bool same = (labr == labc[n]);
                if (same) {
                    if (row_g != coln[n]) pm = fmaxf(pm, d2);
                } else {
                    nm = fminf(nm, d2);
                }
            }
#pragma unroll
            for (int off = 1; off < 16; off <<= 1) {
                pm = fmaxf(pm, __shfl_xor(pm, off));
                nm = fminf(nm, __shfl_xor(nm, off));
            }
            if (lo == 0) {
                atomicMax(&posmax[row_g], __float_as_uint(pm));
                atomicMin(&negmin[row_g], __float_as_uint(nm));
            }
        }
    }
}

// ---- final reduction + scalar combine (sqrt deferred to here; float32 outputs) ----
__global__ __launch_bounds__(256) void finalize_kernel(const unsigned* __restrict__ posmax,
                                                       const unsigned* __restrict__ negmin,
                                                       const float* __restrict__ fpart,
                                                       const float* __restrict__ kpart,
                                                       float* __restrict__ out) {
    int tid = threadIdx.x;
    float sum_pr = 0.f, sum_v = 0.f;
    for (int i = tid; i < B_ROWS; i += 256) {
        float p2 = __uint_as_float(posmax[i]);
        float n2 = __uint_as_float(negmin[i]);
        float v = (p2 > 0.f) ? 1.f : 0.f;
        sum_pr += fmaxf(sqrtf(p2) - sqrtf(n2) + 0.3f, 0.f) * v;
        sum_v += v;
    }
    sum_pr = waveReduceSum(sum_pr);
    sum_v = waveReduceSum(sum_v);
    __shared__ float sp[4], sv[4];
    int wave = tid >> 6, lane = tid & 63;
    if (lane == 0) { sp[wave] = sum_pr; sv[wave] = sum_v; }
    __syncthreads();
    if (tid == 0) {
        float spr = sp[0] + sp[1] + sp[2] + sp[3];
        float svv = sv[0] + sv[1] + sv[2] + sv[3];
        float fsum = 0.f, ksum = 0.f;
        for (int b = 0; b < 16; ++b) { fsum += fpart[b]; ksum += kpart[b]; }
        float focal = fsum / 4096.f;
        float kd = ksum / 4096.f * 9.f;  // * T^2
        float triplet = (svv > 0.f) ? spr / fmaxf(svv, 1.f) : 0.f;
        float total = focal + 0.5f * triplet + kd;
        out[0] = total;
        out[1] = focal;
        out[2] = triplet;
        out[3] = kd;
    }
}

extern "C" void kernel_launch(void* const* d_in, const int* in_sizes, int n_in,
                              void* d_out, int out_size, void* d_ws, size_t ws_size,
                              hipStream_t stream) {
    const float* logits = (const float*)d_in[0];
    const float* feat   = (const float*)d_in[1];
    const int*   labels = (const int*)d_in[2];
    const float* soft   = (const float*)d_in[3];

    char* ws = (char*)d_ws;
    unsigned* posmax = (unsigned*)ws;                    // 4096 u32 (d^2 bits)
    unsigned* negmin = (unsigned*)(ws + 16384);          // 4096 u32 (d^2 bits)
    float*    sqn    = (float*)(ws + 32768);             // 4096 f32
    float*    fpart  = (float*)(ws + 49152);             // 16 f32
    float*    kpart  = (float*)(ws + 49152 + 256);       // 16 f32
    short*    featbf = (short*)(ws + 65536);             // 4096*512 bf16 = 4 MB

    prep_kernel<<<1024, 256, 0, stream>>>(feat, logits, labels, soft, featbf, sqn,
                                          posmax, (float*)negmin, fpart, kpart);
    dim3 grid(32, 32);
    pairwise_glds_kernel<<<grid, 256, 0, stream>>>(featbf, sqn, labels, posmax, negmin);
    finalize_kernel<<<1, 256, 0, stream>>>(posmax, negmin, fpart, kpart,
                                           (float*)d_out);
}

// Round 6
// 59.952 us; speedup vs baseline: 1.4106x; 1.0238x over previous
//
#include <hip/hip_runtime.h>
#include <hip/hip_bf16.h>

#define B_ROWS 4096
#define D_FEAT 512

typedef short s16x8 __attribute__((ext_vector_type(8)));
typedef float f32x4 __attribute__((ext_vector_type(4)));

#define GLOAD_LDS16(gsrc, ldst)                                                        \
    __builtin_amdgcn_global_load_lds(                                                  \
        (const __attribute__((address_space(1))) void*)(gsrc),                         \
        (__attribute__((address_space(3))) void*)(ldst), 16, 0, 0)

__device__ inline float waveReduceSum(float v) {
#pragma unroll
    for (int off = 32; off > 0; off >>= 1) v += __shfl_xor(v, off);
    return v;
}

// ---- prep: fp32->bf16 convert + sqnorm(rounded) + ws init; blocks 0..15 also do focal+KD ----
__global__ __launch_bounds__(256) void prep_kernel(const float* __restrict__ feat,
                                                   const float* __restrict__ logits,
                                                   const int* __restrict__ labels,
                                                   const float* __restrict__ soft,
                                                   short* __restrict__ featbf,
                                                   float* __restrict__ sqn,
                                                   unsigned* __restrict__ posmax,
                                                   float* __restrict__ negminf,
                                                   float* __restrict__ fpart,
                                                   float* __restrict__ kpart) {
    const int bid = blockIdx.x, tid = threadIdx.x;
    const int wave = tid >> 6, lane = tid & 63;
    const int row = bid * 4 + wave;

    const float* p = feat + (size_t)row * D_FEAT + lane * 8;
    float4 a = *(const float4*)p;
    float4 b = *(const float4*)(p + 4);
    float vals[8] = {a.x, a.y, a.z, a.w, b.x, b.y, b.z, b.w};
    short outv[8];
    float s = 0.f;
#pragma unroll
    for (int j = 0; j < 8; ++j) {
        __hip_bfloat16 h = __float2bfloat16(vals[j]);
        outv[j] = *(short*)&h;
        float xb = __bfloat162float(h);
        s = fmaf(xb, xb, s);
    }
    *(s16x8*)(featbf + (size_t)row * D_FEAT + lane * 8) = *(s16x8*)outv;
    s = waveReduceSum(s);
    if (lane == 0) sqn[row] = s;

    if (tid < 4) posmax[bid * 4 + tid] = 0u;
    else if (tid < 8) negminf[bid * 4 + tid - 4] = 1e12f;

    if (bid < 16) {
        int i = bid * 256 + tid;
        float l0 = logits[2 * i], l1 = logits[2 * i + 1];

        float m = fmaxf(l0, l1);
        float lse = m + logf(expf(l0 - m) + expf(l1 - m));
        float lp = (labels[i] ? l1 : l0) - lse;
        float ce = -lp;
        float pt = expf(lp);
        float om = 1.f - pt;
        float focal = om * om * ce;

        const float Tinv = 1.f / 3.f;
        float s0 = l0 * Tinv, s1 = l1 * Tinv;
        float ms = fmaxf(s0, s1);
        float lses = ms + logf(expf(s0 - ms) + expf(s1 - ms));
        float sl0 = s0 - lses, sl1 = s1 - lses;
        float t0 = logf(soft[2 * i] + 1e-8f) * Tinv;
        float t1 = logf(soft[2 * i + 1] + 1e-8f) * Tinv;
        float mt = fmaxf(t0, t1);
        float lset = mt + logf(expf(t0 - mt) + expf(t1 - mt));
        float tl0 = t0 - lset, tl1 = t1 - lset;
        float p0 = expf(tl0), p1 = expf(tl1);
        float kd = p0 * (tl0 - sl0) + p1 * (tl1 - sl1);

        float fs = waveReduceSum(focal);
        float ks = waveReduceSum(kd);
        __shared__ float sf[4], sk[4];
        if (lane == 0) { sf[wave] = fs; sk[wave] = ks; }
        __syncthreads();
        if (tid == 0) {
            fpart[bid] = sf[0] + sf[1] + sf[2] + sf[3];
            kpart[bid] = sk[0] + sk[1] + sk[2] + sk[3];
        }
    }
}

// ---- pairwise d^2 via bf16 MFMA: 128x128 tile, BK=64, DOUBLE-BUFFERED
// global_load_lds staging with counted-drain 2-phase schedule (T3-minimum):
//   prologue: STAGE(buf0); vmcnt(0); s_barrier
//   iter t:   STAGE(buf^1, t+1); ds_read+MFMA(buf); vmcnt(0); s_barrier; swap
// The prefetch's L2 latency hides under the current tile's MFMA. Raw s_barrier
// (not __syncthreads) avoids the lgkmcnt(0)+full-drain the compiler emits.
// Swizzle: chunk' = chunk ^ (row&7), applied on global source + ds_read (rule #21).
__global__ __launch_bounds__(256) void pairwise_db_kernel(const short* __restrict__ featbf,
                                                          const float* __restrict__ sqn,
                                                          const int* __restrict__ labels,
                                                          unsigned* __restrict__ posmax,
                                                          unsigned* __restrict__ negmin) {
    __shared__ short As0[128 * 64], As1[128 * 64];
    __shared__ short Bs0[128 * 64], Bs1[128 * 64];
    const int tid = threadIdx.x;
    const int jb = blockIdx.x, ib = blockIdx.y;
    const int wid = tid >> 6, lane = tid & 63;
    const int wr = wid >> 1, wc = wid & 1;
    const int lo = lane & 15, hi = lane >> 4;

    // staging: 16 segments of 1KB per tile; wave stages segments wid*4..wid*4+3.
    const short* Asrc[4];
    const short* Bsrc[4];
    int dstoff[4];
#pragma unroll
    for (int q = 0; q < 4; ++q) {
        int seg = wid * 4 + q;
        int row = seg * 8 + (lane >> 3);
        int c = (lane & 7) ^ (row & 7);
        Asrc[q] = featbf + (size_t)(ib * 128 + row) * D_FEAT + c * 8;
        Bsrc[q] = featbf + (size_t)(jb * 128 + row) * D_FEAT + c * 8;
        dstoff[q] = seg * 512;  // shorts; wave-uniform base, HW adds lane*16B
    }

    // fragment ds_read offsets (in shorts), same involution as the source swizzle
    int aoff[2][4], boff[2][4];
#pragma unroll
    for (int ks = 0; ks < 2; ++ks) {
#pragma unroll
        for (int m = 0; m < 4; ++m) {
            int ar = wr * 64 + m * 16 + lo;
            aoff[ks][m] = ar * 64 + ((ks * 4 + hi) ^ (ar & 7)) * 8;
            int bc = wc * 64 + m * 16 + lo;
            boff[ks][m] = bc * 64 + ((ks * 4 + hi) ^ (bc & 7)) * 8;
        }
    }

    f32x4 acc[4][4];
#pragma unroll
    for (int m = 0; m < 4; ++m)
#pragma unroll
        for (int n = 0; n < 4; ++n)
            acc[m][n] = (f32x4){0.f, 0.f, 0.f, 0.f};

#define STAGE_TILE(Adst, Bdst, kkv)                                                    \
    {                                                                                  \
        _Pragma("unroll") for (int q = 0; q < 4; ++q) {                                \
            GLOAD_LDS16(Asrc[q] + (kkv) * 64, (Adst) + dstoff[q]);                     \
            GLOAD_LDS16(Bsrc[q] + (kkv) * 64, (Bdst) + dstoff[q]);                     \
        }                                                                              \
    }

#define COMPUTE_TILE(Abuf, Bbuf)                                                       \
    {                                                                                  \
        _Pragma("unroll") for (int ks = 0; ks < 2; ++ks) {                             \
            s16x8 af[4], bfr[4];                                                       \
            _Pragma("unroll") for (int m = 0; m < 4; ++m)                              \
                af[m] = *(const s16x8*)((Abuf) + aoff[ks][m]);                         \
            _Pragma("unroll") for (int n = 0; n < 4; ++n)                              \
                bfr[n] = *(const s16x8*)((Bbuf) + boff[ks][n]);                        \
            _Pragma("unroll") for (int m = 0; m < 4; ++m)                              \
                _Pragma("unroll") for (int n = 0; n < 4; ++n)                          \
                    acc[m][n] = __builtin_amdgcn_mfma_f32_16x16x32_bf16(               \
                        af[m], bfr[n], acc[m][n], 0, 0, 0);                            \
        }                                                                              \
    }

    short *Aa = As0, *Ab = As1, *Ba = Bs0, *Bb = Bs1;
    STAGE_TILE(Aa, Ba, 0);
    asm volatile("s_waitcnt vmcnt(0)" ::: "memory");
    __builtin_amdgcn_s_barrier();
    __builtin_amdgcn_sched_barrier(0);

    for (int kk = 0; kk < D_FEAT / 64 - 1; ++kk) {
        STAGE_TILE(Ab, Bb, kk + 1);   // prefetch next tile (latency hides under MFMA)
        COMPUTE_TILE(Aa, Ba);
        asm volatile("s_waitcnt vmcnt(0)" ::: "memory");  // own prefetch landed
        __builtin_amdgcn_s_barrier();                     // all waves: next tile ready
        __builtin_amdgcn_sched_barrier(0);
        short* t;
        t = Aa; Aa = Ab; Ab = t;
        t = Ba; Ba = Bb; Bb = t;
    }
    COMPUTE_TILE(Aa, Ba);

#undef STAGE_TILE
#undef COMPUTE_TILE

    // ---- epilogue in d^2 domain (C/D layout m89: col = lo, row = hi*4 + reg) ----
    int coln[4], labc[4];
    float sqc[4];
#pragma unroll
    for (int n = 0; n < 4; ++n) {
        coln[n] = jb * 128 + wc * 64 + n * 16 + lo;
        labc[n] = labels[coln[n]];
        sqc[n] = sqn[coln[n]];
    }
#pragma unroll
    for (int m = 0; m < 4; ++m) {
#pragma unroll
        for (int r = 0; r < 4; ++r) {
            int row_g = ib * 128 + wr * 64 + m * 16 + hi * 4 + r;
            int labr = labels[row_g];
            float sqr = sqn[row_g];
            float pm = 0.f, nm = 1e12f;
#pragma unroll
            for (int n = 0; n < 4; ++n) {
                float d2 = fmaxf(sqr + fmaf(-2.f, acc[m][n][r], sqc[n]), 0.f);
                bool same = (labr == labc[n]);
                if (same) {
                    if (row_g != coln[n]) pm = fmaxf(pm, d2);
                } else {
                    nm = fminf(nm, d2);
                }
            }
#pragma unroll
            for (int off = 1; off < 16; off <<= 1) {
                pm = fmaxf(pm, __shfl_xor(pm, off));
                nm = fminf(nm, __shfl_xor(nm, off));
            }
            if (lo == 0) {
                atomicMax(&posmax[row_g], __float_as_uint(pm));
                atomicMin(&negmin[row_g], __float_as_uint(nm));
            }
        }
    }
}

// ---- final reduction + scalar combine (sqrt deferred to here; float32 outputs) ----
__global__ __launch_bounds__(256) void finalize_kernel(const unsigned* __restrict__ posmax,
                                                       const unsigned* __restrict__ negmin,
                                                       const float* __restrict__ fpart,
                                                       const float* __restrict__ kpart,
                                                       float* __restrict__ out) {
    int tid = threadIdx.x;
    float sum_pr = 0.f, sum_v = 0.f;
    for (int i = tid; i < B_ROWS; i += 256) {
        float p2 = __uint_as_float(posmax[i]);
        float n2 = __uint_as_float(negmin[i]);
        float v = (p2 > 0.f) ? 1.f : 0.f;
        sum_pr += fmaxf(sqrtf(p2) - sqrtf(n2) + 0.3f, 0.f) * v;
        sum_v += v;
    }
    sum_pr = waveReduceSum(sum_pr);
    sum_v = waveReduceSum(sum_v);
    __shared__ float sp[4], sv[4];
    int wave = tid >> 6, lane = tid & 63;
    if (lane == 0) { sp[wave] = sum_pr; sv[wave] = sum_v; }
    __syncthreads();
    if (tid == 0) {
        float spr = sp[0] + sp[1] + sp[2] + sp[3];
        float svv = sv[0] + sv[1] + sv[2] + sv[3];
        float fsum = 0.f, ksum = 0.f;
        for (int b = 0; b < 16; ++b) { fsum += fpart[b]; ksum += kpart[b]; }
        float focal = fsum / 4096.f;
        float kd = ksum / 4096.f * 9.f;  // * T^2
        float triplet = (svv > 0.f) ? spr / fmaxf(svv, 1.f) : 0.f;
        float total = focal + 0.5f * triplet + kd;
        out[0] = total;
        out[1] = focal;
        out[2] = triplet;
        out[3] = kd;
    }
}

extern "C" void kernel_launch(void* const* d_in, const int* in_sizes, int n_in,
                              void* d_out, int out_size, void* d_ws, size_t ws_size,
                              hipStream_t stream) {
    const float* logits = (const float*)d_in[0];
    const float* feat   = (const float*)d_in[1];
    const int*   labels = (const int*)d_in[2];
    const float* soft   = (const float*)d_in[3];

    char* ws = (char*)d_ws;
    unsigned* posmax = (unsigned*)ws;                    // 4096 u32 (d^2 bits)
    unsigned* negmin = (unsigned*)(ws + 16384);          // 4096 u32 (d^2 bits)
    float*    sqn    = (float*)(ws + 32768);             // 4096 f32
    float*    fpart  = (float*)(ws + 49152);             // 16 f32
    float*    kpart  = (float*)(ws + 49152 + 256);       // 16 f32
    short*    featbf = (short*)(ws + 65536);             // 4096*512 bf16 = 4 MB

    prep_kernel<<<1024, 256, 0, stream>>>(feat, logits, labels, soft, featbf, sqn,
                                          posmax, (float*)negmin, fpart, kpart);
    dim3 grid(32, 32);
    pairwise_db_kernel<<<grid, 256, 0, stream>>>(featbf, sqn, labels, posmax, negmin);
    finalize_kernel<<<1, 256, 0, stream>>>(posmax, negmin, fpart, kpart,
                                           (float*)d_out);
}

// Round 7
// 56.828 us; speedup vs baseline: 1.4881x; 1.0550x over previous
//
#include <hip/hip_runtime.h>
#include <hip/hip_bf16.h>

#define B_ROWS 4096
#define D_FEAT 512

typedef short s16x8 __attribute__((ext_vector_type(8)));
typedef float f32x4 __attribute__((ext_vector_type(4)));

#define GLOAD_LDS16(gsrc, ldst)                                                        \
    __builtin_amdgcn_global_load_lds(                                                  \
        (const __attribute__((address_space(1))) void*)(gsrc),                         \
        (__attribute__((address_space(3))) void*)(ldst), 16, 0, 0)

__device__ inline float waveReduceSum(float v) {
#pragma unroll
    for (int off = 32; off > 0; off >>= 1) v += __shfl_xor(v, off);
    return v;
}

// ---- prep: fp32->bf16 convert + sqnorm(rounded) + ws init; blocks 0..15 also do focal+KD ----
__global__ __launch_bounds__(256) void prep_kernel(const float* __restrict__ feat,
                                                   const float* __restrict__ logits,
                                                   const int* __restrict__ labels,
                                                   const float* __restrict__ soft,
                                                   short* __restrict__ featbf,
                                                   float* __restrict__ sqn,
                                                   unsigned* __restrict__ posmax,
                                                   float* __restrict__ negminf,
                                                   float* __restrict__ fpart,
                                                   float* __restrict__ kpart) {
    const int bid = blockIdx.x, tid = threadIdx.x;
    const int wave = tid >> 6, lane = tid & 63;
    const int row = bid * 4 + wave;

    const float* p = feat + (size_t)row * D_FEAT + lane * 8;
    float4 a = *(const float4*)p;
    float4 b = *(const float4*)(p + 4);
    float vals[8] = {a.x, a.y, a.z, a.w, b.x, b.y, b.z, b.w};
    short outv[8];
    float s = 0.f;
#pragma unroll
    for (int j = 0; j < 8; ++j) {
        __hip_bfloat16 h = __float2bfloat16(vals[j]);
        outv[j] = *(short*)&h;
        float xb = __bfloat162float(h);
        s = fmaf(xb, xb, s);
    }
    *(s16x8*)(featbf + (size_t)row * D_FEAT + lane * 8) = *(s16x8*)outv;
    s = waveReduceSum(s);
    if (lane == 0) sqn[row] = s;

    if (tid < 4) posmax[bid * 4 + tid] = 0u;
    else if (tid < 8) negminf[bid * 4 + tid - 4] = 1e12f;

    if (bid < 16) {
        int i = bid * 256 + tid;
        float l0 = logits[2 * i], l1 = logits[2 * i + 1];

        float m = fmaxf(l0, l1);
        float lse = m + logf(expf(l0 - m) + expf(l1 - m));
        float lp = (labels[i] ? l1 : l0) - lse;
        float ce = -lp;
        float pt = expf(lp);
        float om = 1.f - pt;
        float focal = om * om * ce;

        const float Tinv = 1.f / 3.f;
        float s0 = l0 * Tinv, s1 = l1 * Tinv;
        float ms = fmaxf(s0, s1);
        float lses = ms + logf(expf(s0 - ms) + expf(s1 - ms));
        float sl0 = s0 - lses, sl1 = s1 - lses;
        float t0 = logf(soft[2 * i] + 1e-8f) * Tinv;
        float t1 = logf(soft[2 * i + 1] + 1e-8f) * Tinv;
        float mt = fmaxf(t0, t1);
        float lset = mt + logf(expf(t0 - mt) + expf(t1 - mt));
        float tl0 = t0 - lset, tl1 = t1 - lset;
        float p0 = expf(tl0), p1 = expf(tl1);
        float kd = p0 * (tl0 - sl0) + p1 * (tl1 - sl1);

        float fs = waveReduceSum(focal);
        float ks = waveReduceSum(kd);
        __shared__ float sf[4], sk[4];
        if (lane == 0) { sf[wave] = fs; sk[wave] = ks; }
        __syncthreads();
        if (tid == 0) {
            fpart[bid] = sf[0] + sf[1] + sf[2] + sf[3];
            kpart[bid] = sk[0] + sk[1] + sk[2] + sk[3];
        }
    }
}

// ---- pairwise d^2 via bf16 MFMA: 256x256 tile, 8 waves (2Mx4N), BK=64,
// double-buffered global_load_lds staging, 2-phase counted schedule:
//   prologue: STAGE(buf0); vmcnt(0); s_barrier
//   iter:     STAGE(buf^1, kk+1); COMPUTE(buf); vmcnt(0); s_barrier; swap
// Per-wave output 128x64 = 8x4 frags of mfma_f32_16x16x32_bf16 (64 MFMA/K-step).
// Swizzle: chunk' = chunk ^ (row&7) on global source + ds_read (involution, rule #21).
// LDS: 4 x 32 KB = 128 KB -> 1 block/CU, 8 waves.
__global__ __launch_bounds__(512) void pairwise_256_kernel(const short* __restrict__ featbf,
                                                           const float* __restrict__ sqn,
                                                           const int* __restrict__ labels,
                                                           unsigned* __restrict__ posmax,
                                                           unsigned* __restrict__ negmin) {
    __shared__ short As0[256 * 64], As1[256 * 64];
    __shared__ short Bs0[256 * 64], Bs1[256 * 64];
    const int tid = threadIdx.x;
    const int jb = blockIdx.x, ib = blockIdx.y;
    const int wid = tid >> 6, lane = tid & 63;
    const int wr = wid >> 2, wc = wid & 3;   // 2 x 4 wave grid
    const int lo = lane & 15, hi = lane >> 4;

    // staging: tile = 256 rows x 64 bf16 (128B rows, 8 chunks of 16B) = 32 KB.
    // 512 threads x 16B = 8 KB per issue -> 4 issues each for A and B.
    // issue q: row = q*64 + wid*8 + (lane>>3), chunk' = lane&7, src chunk = chunk'^(row&7).
    // LDS dst offset = (q*64 + wid*8)*128B + lane*16B  (wave-uniform base + lane*16).
    const short* Asrc[4];
    const short* Bsrc[4];
    int dstoff[4];
#pragma unroll
    for (int q = 0; q < 4; ++q) {
        int row = q * 64 + wid * 8 + (lane >> 3);
        int c = (lane & 7) ^ (row & 7);
        Asrc[q] = featbf + (size_t)(ib * 256 + row) * D_FEAT + c * 8;
        Bsrc[q] = featbf + (size_t)(jb * 256 + row) * D_FEAT + c * 8;
        dstoff[q] = (q * 64 + wid * 8) * 64;  // shorts
    }

    // fragment ds_read offsets (shorts), same involution
    int aoff[2][8], boff[2][4];
#pragma unroll
    for (int ks = 0; ks < 2; ++ks) {
#pragma unroll
        for (int m = 0; m < 8; ++m) {
            int ar = wr * 128 + m * 16 + lo;
            aoff[ks][m] = ar * 64 + ((ks * 4 + hi) ^ (ar & 7)) * 8;
        }
#pragma unroll
        for (int n = 0; n < 4; ++n) {
            int bc = wc * 64 + n * 16 + lo;
            boff[ks][n] = bc * 64 + ((ks * 4 + hi) ^ (bc & 7)) * 8;
        }
    }

    f32x4 acc[8][4];
#pragma unroll
    for (int m = 0; m < 8; ++m)
#pragma unroll
        for (int n = 0; n < 4; ++n)
            acc[m][n] = (f32x4){0.f, 0.f, 0.f, 0.f};

#define STAGE_TILE(Adst, Bdst, kkv)                                                    \
    {                                                                                  \
        _Pragma("unroll") for (int q = 0; q < 4; ++q) {                                \
            GLOAD_LDS16(Asrc[q] + (kkv) * 64, (Adst) + dstoff[q]);                     \
            GLOAD_LDS16(Bsrc[q] + (kkv) * 64, (Bdst) + dstoff[q]);                     \
        }                                                                              \
    }

#define COMPUTE_TILE(Abuf, Bbuf)                                                       \
    {                                                                                  \
        _Pragma("unroll") for (int ks = 0; ks < 2; ++ks) {                             \
            s16x8 af[8], bfr[4];                                                       \
            _Pragma("unroll") for (int m = 0; m < 8; ++m)                              \
                af[m] = *(const s16x8*)((Abuf) + aoff[ks][m]);                         \
            _Pragma("unroll") for (int n = 0; n < 4; ++n)                              \
                bfr[n] = *(const s16x8*)((Bbuf) + boff[ks][n]);                        \
            _Pragma("unroll") for (int m = 0; m < 8; ++m)                              \
                _Pragma("unroll") for (int n = 0; n < 4; ++n)                          \
                    acc[m][n] = __builtin_amdgcn_mfma_f32_16x16x32_bf16(               \
                        af[m], bfr[n], acc[m][n], 0, 0, 0);                            \
        }                                                                              \
    }

    short *Aa = As0, *Ab = As1, *Ba = Bs0, *Bb = Bs1;
    STAGE_TILE(Aa, Ba, 0);
    asm volatile("s_waitcnt vmcnt(0)" ::: "memory");
    __builtin_amdgcn_s_barrier();
    __builtin_amdgcn_sched_barrier(0);

    for (int kk = 0; kk < D_FEAT / 64 - 1; ++kk) {
        STAGE_TILE(Ab, Bb, kk + 1);   // prefetch next tile under current compute
        COMPUTE_TILE(Aa, Ba);
        asm volatile("s_waitcnt vmcnt(0)" ::: "memory");
        __builtin_amdgcn_s_barrier();
        __builtin_amdgcn_sched_barrier(0);
        short* t;
        t = Aa; Aa = Ab; Ab = t;
        t = Ba; Ba = Bb; Bb = t;
    }
    COMPUTE_TILE(Aa, Ba);

#undef STAGE_TILE
#undef COMPUTE_TILE

    // ---- epilogue in d^2 domain (C/D layout m89: col = lo, row = hi*4 + reg) ----
    int coln[4], labc[4];
    float sqc[4];
#pragma unroll
    for (int n = 0; n < 4; ++n) {
        coln[n] = jb * 256 + wc * 64 + n * 16 + lo;
        labc[n] = labels[coln[n]];
        sqc[n] = sqn[coln[n]];
    }
#pragma unroll
    for (int m = 0; m < 8; ++m) {
#pragma unroll
        for (int r = 0; r < 4; ++r) {
            int row_g = ib * 256 + wr * 128 + m * 16 + hi * 4 + r;
            int labr = labels[row_g];
            float sqr = sqn[row_g];
            float pm = 0.f, nm = 1e12f;
#pragma unroll
            for (int n = 0; n < 4; ++n) {
                float d2 = fmaxf(sqr + fmaf(-2.f, acc[m][n][r], sqc[n]), 0.f);
                bool same = (labr == labc[n]);
                if (same) {
                    if (row_g != coln[n]) pm = fmaxf(pm, d2);
                } else {
                    nm = fminf(nm, d2);
                }
            }
#pragma unroll
            for (int off = 1; off < 16; off <<= 1) {
                pm = fmaxf(pm, __shfl_xor(pm, off));
                nm = fminf(nm, __shfl_xor(nm, off));
            }
            if (lo == 0) {
                atomicMax(&posmax[row_g], __float_as_uint(pm));
                atomicMin(&negmin[row_g], __float_as_uint(nm));
            }
        }
    }
}

// ---- final reduction + scalar combine (sqrt deferred to here; float32 outputs) ----
__global__ __launch_bounds__(256) void finalize_kernel(const unsigned* __restrict__ posmax,
                                                       const unsigned* __restrict__ negmin,
                                                       const float* __restrict__ fpart,
                                                       const float* __restrict__ kpart,
                                                       float* __restrict__ out) {
    int tid = threadIdx.x;
    float sum_pr = 0.f, sum_v = 0.f;
    for (int i = tid; i < B_ROWS; i += 256) {
        float p2 = __uint_as_float(posmax[i]);
        float n2 = __uint_as_float(negmin[i]);
        float v = (p2 > 0.f) ? 1.f : 0.f;
        sum_pr += fmaxf(sqrtf(p2) - sqrtf(n2) + 0.3f, 0.f) * v;
        sum_v += v;
    }
    sum_pr = waveReduceSum(sum_pr);
    sum_v = waveReduceSum(sum_v);
    __shared__ float sp[4], sv[4];
    int wave = tid >> 6, lane = tid & 63;
    if (lane == 0) { sp[wave] = sum_pr; sv[wave] = sum_v; }
    __syncthreads();
    if (tid == 0) {
        float spr = sp[0] + sp[1] + sp[2] + sp[3];
        float svv = sv[0] + sv[1] + sv[2] + sv[3];
        float fsum = 0.f, ksum = 0.f;
        for (int b = 0; b < 16; ++b) { fsum += fpart[b]; ksum += kpart[b]; }
        float focal = fsum / 4096.f;
        float kd = ksum / 4096.f * 9.f;  // * T^2
        float triplet = (svv > 0.f) ? spr / fmaxf(svv, 1.f) : 0.f;
        float total = focal + 0.5f * triplet + kd;
        out[0] = total;
        out[1] = focal;
        out[2] = triplet;
        out[3] = kd;
    }
}

extern "C" void kernel_launch(void* const* d_in, const int* in_sizes, int n_in,
                              void* d_out, int out_size, void* d_ws, size_t ws_size,
                              hipStream_t stream) {
    const float* logits = (const float*)d_in[0];
    const float* feat   = (const float*)d_in[1];
    const int*   labels = (const int*)d_in[2];
    const float* soft   = (const float*)d_in[3];

    char* ws = (char*)d_ws;
    unsigned* posmax = (unsigned*)ws;                    // 4096 u32 (d^2 bits)
    unsigned* negmin = (unsigned*)(ws + 16384);          // 4096 u32 (d^2 bits)
    float*    sqn    = (float*)(ws + 32768);             // 4096 f32
    float*    fpart  = (float*)(ws + 49152);             // 16 f32
    float*    kpart  = (float*)(ws + 49152 + 256);       // 16 f32
    short*    featbf = (short*)(ws + 65536);             // 4096*512 bf16 = 4 MB

    prep_kernel<<<1024, 256, 0, stream>>>(feat, logits, labels, soft, featbf, sqn,
                                          posmax, (float*)negmin, fpart, kpart);
    dim3 grid(16, 16);
    pairwise_256_kernel<<<grid, 512, 0, stream>>>(featbf, sqn, labels, posmax, negmin);
    finalize_kernel<<<1, 256, 0, stream>>>(posmax, negmin, fpart, kpart,
                                           (float*)d_out);
}

// Round 8
// 46.031 us; speedup vs baseline: 1.8372x; 1.2346x over previous
//
#include <hip/hip_runtime.h>
#include <hip/hip_bf16.h>

#define B_ROWS 4096
#define D_FEAT 512

typedef short s16x8 __attribute__((ext_vector_type(8)));
typedef float f32x4 __attribute__((ext_vector_type(4)));

#define GLOAD_LDS16(gsrc, ldst)                                                        \
    __builtin_amdgcn_global_load_lds(                                                  \
        (const __attribute__((address_space(1))) void*)(gsrc),                         \
        (__attribute__((address_space(3))) void*)(ldst), 16, 0, 0)

__device__ inline float waveReduceSum(float v) {
#pragma unroll
    for (int off = 32; off > 0; off >>= 1) v += __shfl_xor(v, off);
    return v;
}

// ---- prep: fp32->bf16 convert + sqnorm(rounded) + ws init; blocks 0..15 also do focal+KD ----
__global__ __launch_bounds__(256) void prep_kernel(const float* __restrict__ feat,
                                                   const float* __restrict__ logits,
                                                   const int* __restrict__ labels,
                                                   const float* __restrict__ soft,
                                                   short* __restrict__ featbf,
                                                   float* __restrict__ sqn,
                                                   unsigned* __restrict__ posmax,
                                                   float* __restrict__ negminf,
                                                   float* __restrict__ fpart,
                                                   float* __restrict__ kpart) {
    const int bid = blockIdx.x, tid = threadIdx.x;
    const int wave = tid >> 6, lane = tid & 63;
    const int row = bid * 4 + wave;

    const float* p = feat + (size_t)row * D_FEAT + lane * 8;
    float4 a = *(const float4*)p;
    float4 b = *(const float4*)(p + 4);
    float vals[8] = {a.x, a.y, a.z, a.w, b.x, b.y, b.z, b.w};
    short outv[8];
    float s = 0.f;
#pragma unroll
    for (int j = 0; j < 8; ++j) {
        __hip_bfloat16 h = __float2bfloat16(vals[j]);
        outv[j] = *(short*)&h;
        float xb = __bfloat162float(h);
        s = fmaf(xb, xb, s);
    }
    *(s16x8*)(featbf + (size_t)row * D_FEAT + lane * 8) = *(s16x8*)outv;
    s = waveReduceSum(s);
    if (lane == 0) sqn[row] = s;

    if (tid < 4) posmax[bid * 4 + tid] = 0u;
    else if (tid < 8) negminf[bid * 4 + tid - 4] = 1e12f;

    if (bid < 16) {
        int i = bid * 256 + tid;
        float l0 = logits[2 * i], l1 = logits[2 * i + 1];

        float m = fmaxf(l0, l1);
        float lse = m + logf(expf(l0 - m) + expf(l1 - m));
        float lp = (labels[i] ? l1 : l0) - lse;
        float ce = -lp;
        float pt = expf(lp);
        float om = 1.f - pt;
        float focal = om * om * ce;

        const float Tinv = 1.f / 3.f;
        float s0 = l0 * Tinv, s1 = l1 * Tinv;
        float ms = fmaxf(s0, s1);
        float lses = ms + logf(expf(s0 - ms) + expf(s1 - ms));
        float sl0 = s0 - lses, sl1 = s1 - lses;
        float t0 = logf(soft[2 * i] + 1e-8f) * Tinv;
        float t1 = logf(soft[2 * i + 1] + 1e-8f) * Tinv;
        float mt = fmaxf(t0, t1);
        float lset = mt + logf(expf(t0 - mt) + expf(t1 - mt));
        float tl0 = t0 - lset, tl1 = t1 - lset;
        float p0 = expf(tl0), p1 = expf(tl1);
        float kd = p0 * (tl0 - sl0) + p1 * (tl1 - sl1);

        float fs = waveReduceSum(focal);
        float ks = waveReduceSum(kd);
        __shared__ float sf[4], sk[4];
        if (lane == 0) { sf[wave] = fs; sk[wave] = ks; }
        __syncthreads();
        if (tid == 0) {
            fpart[bid] = sf[0] + sf[1] + sf[2] + sf[3];
            kpart[bid] = sk[0] + sk[1] + sk[2] + sk[3];
        }
    }
}

// ---- pairwise d^2 via bf16 MFMA: 256x256 tile, 8 waves (2Mx4N), BK=64, dbuf
// global_load_lds, 2-phase schedule. NEW vs r7: (a) epilogue reduces the 4 wc-waves
// through LDS (reusing dead As0) -> ONE atomic pair per row per block (atomics /4,
// device-scope atomic = memory-side traffic: WRITE_SIZE 8MB -> 2MB); (b) bijective
// XCD-aware block swizzle: each XCD owns a 4(ib)x8(jb) region (3MB working set).
__global__ __launch_bounds__(512) void pairwise_256_kernel(const short* __restrict__ featbf,
                                                           const float* __restrict__ sqn,
                                                           const int* __restrict__ labels,
                                                           unsigned* __restrict__ posmax,
                                                           unsigned* __restrict__ negmin) {
    __shared__ short As0[256 * 64], As1[256 * 64];
    __shared__ short Bs0[256 * 64], Bs1[256 * 64];
    const int tid = threadIdx.x;
    // XCD swizzle (blocks round-robin XCDs by blockIdx%8, m09): XCD x gets a
    // contiguous 4x8 (ib,jb) region; bijective for grid=256.
    const int bfl = blockIdx.x;
    const int xcd = bfl & 7, loc = bfl >> 3;
    const int ib = (xcd & 3) * 4 + (loc & 3);
    const int jb = (xcd >> 1 & 2) * 4 + (loc >> 2);
    const int wid = tid >> 6, lane = tid & 63;
    const int wr = wid >> 2, wc = wid & 3;   // 2 x 4 wave grid
    const int lo = lane & 15, hi = lane >> 4;

    const short* Asrc[4];
    const short* Bsrc[4];
    int dstoff[4];
#pragma unroll
    for (int q = 0; q < 4; ++q) {
        int row = q * 64 + wid * 8 + (lane >> 3);
        int c = (lane & 7) ^ (row & 7);
        Asrc[q] = featbf + (size_t)(ib * 256 + row) * D_FEAT + c * 8;
        Bsrc[q] = featbf + (size_t)(jb * 256 + row) * D_FEAT + c * 8;
        dstoff[q] = (q * 64 + wid * 8) * 64;  // shorts
    }

    int aoff[2][8], boff[2][4];
#pragma unroll
    for (int ks = 0; ks < 2; ++ks) {
#pragma unroll
        for (int m = 0; m < 8; ++m) {
            int ar = wr * 128 + m * 16 + lo;
            aoff[ks][m] = ar * 64 + ((ks * 4 + hi) ^ (ar & 7)) * 8;
        }
#pragma unroll
        for (int n = 0; n < 4; ++n) {
            int bc = wc * 64 + n * 16 + lo;
            boff[ks][n] = bc * 64 + ((ks * 4 + hi) ^ (bc & 7)) * 8;
        }
    }

    f32x4 acc[8][4];
#pragma unroll
    for (int m = 0; m < 8; ++m)
#pragma unroll
        for (int n = 0; n < 4; ++n)
            acc[m][n] = (f32x4){0.f, 0.f, 0.f, 0.f};

#define STAGE_TILE(Adst, Bdst, kkv)                                                    \
    {                                                                                  \
        _Pragma("unroll") for (int q = 0; q < 4; ++q) {                                \
            GLOAD_LDS16(Asrc[q] + (kkv) * 64, (Adst) + dstoff[q]);                     \
            GLOAD_LDS16(Bsrc[q] + (kkv) * 64, (Bdst) + dstoff[q]);                     \
        }                                                                              \
    }

#define COMPUTE_TILE(Abuf, Bbuf)                                                       \
    {                                                                                  \
        _Pragma("unroll") for (int ks = 0; ks < 2; ++ks) {                             \
            s16x8 af[8], bfr[4];                                                       \
            _Pragma("unroll") for (int m = 0; m < 8; ++m)                              \
                af[m] = *(const s16x8*)((Abuf) + aoff[ks][m]);                         \
            _Pragma("unroll") for (int n = 0; n < 4; ++n)                              \
                bfr[n] = *(const s16x8*)((Bbuf) + boff[ks][n]);                        \
            _Pragma("unroll") for (int m = 0; m < 8; ++m)                              \
                _Pragma("unroll") for (int n = 0; n < 4; ++n)                          \
                    acc[m][n] = __builtin_amdgcn_mfma_f32_16x16x32_bf16(               \
                        af[m], bfr[n], acc[m][n], 0, 0, 0);                            \
        }                                                                              \
    }

    short *Aa = As0, *Ab = As1, *Ba = Bs0, *Bb = Bs1;
    STAGE_TILE(Aa, Ba, 0);
    asm volatile("s_waitcnt vmcnt(0)" ::: "memory");
    __builtin_amdgcn_s_barrier();
    __builtin_amdgcn_sched_barrier(0);

    for (int kk = 0; kk < D_FEAT / 64 - 1; ++kk) {
        STAGE_TILE(Ab, Bb, kk + 1);   // prefetch next tile under current compute
        COMPUTE_TILE(Aa, Ba);
        asm volatile("s_waitcnt vmcnt(0)" ::: "memory");
        __builtin_amdgcn_s_barrier();
        __builtin_amdgcn_sched_barrier(0);
        short* t;
        t = Aa; Aa = Ab; Ab = t;
        t = Ba; Ba = Bb; Bb = t;
    }
    COMPUTE_TILE(Aa, Ba);

#undef STAGE_TILE
#undef COMPUTE_TILE

    // ---- epilogue in d^2 domain (C/D layout m89: col = lo, row = hi*4 + reg) ----
    // Per-wave 16-lane shfl reduce -> LDS cross-wave reduce (reuse As0, K-loop done)
    // -> single atomicMax/Min per row per block.
    int coln[4], labc[4];
    float sqc[4];
#pragma unroll
    for (int n = 0; n < 4; ++n) {
        coln[n] = jb * 256 + wc * 64 + n * 16 + lo;
        labc[n] = labels[coln[n]];
        sqc[n] = sqn[coln[n]];
    }
    __syncthreads();  // all waves done with K-loop LDS before reuse
    float (*redp)[5] = (float(*)[5])As0;          // [256][5] pm per wc (stride 5: no bank clash)
    float (*redn)[5] = ((float(*)[5])As0) + 256;  // [256][5] nm per wc

#pragma unroll
    for (int m = 0; m < 8; ++m) {
#pragma unroll
        for (int r = 0; r < 4; ++r) {
            int row_loc = wr * 128 + m * 16 + hi * 4 + r;
            int row_g = ib * 256 + row_loc;
            int labr = labels[row_g];
            float sqr = sqn[row_g];
            float pm = 0.f, nm = 1e12f;
#pragma unroll
            for (int n = 0; n < 4; ++n) {
                float d2 = fmaxf(sqr + fmaf(-2.f, acc[m][n][r], sqc[n]), 0.f);
                bool same = (labr == labc[n]);
                if (same) {
                    if (row_g != coln[n]) pm = fmaxf(pm, d2);
                } else {
                    nm = fminf(nm, d2);
                }
            }
#pragma unroll
            for (int off = 1; off < 16; off <<= 1) {
                pm = fmaxf(pm, __shfl_xor(pm, off));
                nm = fminf(nm, __shfl_xor(nm, off));
            }
            if (lo == 0) {
                redp[row_loc][wc] = pm;
                redn[row_loc][wc] = nm;
            }
        }
    }
    __syncthreads();
    if (tid < 256) {
        float p = fmaxf(fmaxf(redp[tid][0], redp[tid][1]),
                        fmaxf(redp[tid][2], redp[tid][3]));
        atomicMax(&posmax[ib * 256 + tid], __float_as_uint(p));
    } else {
        int row = tid - 256;
        float nn = fminf(fminf(redn[row][0], redn[row][1]),
                         fminf(redn[row][2], redn[row][3]));
        atomicMin(&negmin[ib * 256 + row], __float_as_uint(nn));
    }
}

// ---- final reduction + scalar combine (sqrt deferred to here; float32 outputs) ----
__global__ __launch_bounds__(256) void finalize_kernel(const unsigned* __restrict__ posmax,
                                                       const unsigned* __restrict__ negmin,
                                                       const float* __restrict__ fpart,
                                                       const float* __restrict__ kpart,
                                                       float* __restrict__ out) {
    int tid = threadIdx.x;
    float sum_pr = 0.f, sum_v = 0.f;
    for (int i = tid; i < B_ROWS; i += 256) {
        float p2 = __uint_as_float(posmax[i]);
        float n2 = __uint_as_float(negmin[i]);
        float v = (p2 > 0.f) ? 1.f : 0.f;
        sum_pr += fmaxf(sqrtf(p2) - sqrtf(n2) + 0.3f, 0.f) * v;
        sum_v += v;
    }
    sum_pr = waveReduceSum(sum_pr);
    sum_v = waveReduceSum(sum_v);
    __shared__ float sp[4], sv[4];
    int wave = tid >> 6, lane = tid & 63;
    if (lane == 0) { sp[wave] = sum_pr; sv[wave] = sum_v; }
    __syncthreads();
    if (tid == 0) {
        float spr = sp[0] + sp[1] + sp[2] + sp[3];
        float svv = sv[0] + sv[1] + sv[2] + sv[3];
        float fsum = 0.f, ksum = 0.f;
        for (int b = 0; b < 16; ++b) { fsum += fpart[b]; ksum += kpart[b]; }
        float focal = fsum / 4096.f;
        float kd = ksum / 4096.f * 9.f;  // * T^2
        float triplet = (svv > 0.f) ? spr / fmaxf(svv, 1.f) : 0.f;
        float total = focal + 0.5f * triplet + kd;
        out[0] = total;
        out[1] = focal;
        out[2] = triplet;
        out[3] = kd;
    }
}

extern "C" void kernel_launch(void* const* d_in, const int* in_sizes, int n_in,
                              void* d_out, int out_size, void* d_ws, size_t ws_size,
                              hipStream_t stream) {
    const float* logits = (const float*)d_in[0];
    const float* feat   = (const float*)d_in[1];
    const int*   labels = (const int*)d_in[2];
    const float* soft   = (const float*)d_in[3];

    char* ws = (char*)d_ws;
    unsigned* posmax = (unsigned*)ws;                    // 4096 u32 (d^2 bits)
    unsigned* negmin = (unsigned*)(ws + 16384);          // 4096 u32 (d^2 bits)
    float*    sqn    = (float*)(ws + 32768);             // 4096 f32
    float*    fpart  = (float*)(ws + 49152);             // 16 f32
    float*    kpart  = (float*)(ws + 49152 + 256);       // 16 f32
    short*    featbf = (short*)(ws + 65536);             // 4096*512 bf16 = 4 MB

    prep_kernel<<<1024, 256, 0, stream>>>(feat, logits, labels, soft, featbf, sqn,
                                          posmax, (float*)negmin, fpart, kpart);
    pairwise_256_kernel<<<256, 512, 0, stream>>>(featbf, sqn, labels, posmax, negmin);
    finalize_kernel<<<1, 256, 0, stream>>>(posmax, negmin, fpart, kpart,
                                           (float*)d_out);
}

// Round 9
// 44.227 us; speedup vs baseline: 1.9121x; 1.0408x over previous
//
#include <hip/hip_runtime.h>
#include <hip/hip_bf16.h>

#define B_ROWS 4096
#define D_FEAT 512

typedef short s16x8 __attribute__((ext_vector_type(8)));
typedef float f32x4 __attribute__((ext_vector_type(4)));

#define GLOAD_LDS16(gsrc, ldst)                                                        \
    __builtin_amdgcn_global_load_lds(                                                  \
        (const __attribute__((address_space(1))) void*)(gsrc),                         \
        (__attribute__((address_space(3))) void*)(ldst), 16, 0, 0)

__device__ inline float waveReduceSum(float v) {
#pragma unroll
    for (int off = 32; off > 0; off >>= 1) v += __shfl_xor(v, off);
    return v;
}

// ---- prep: fp32->bf16 convert + sqnorm(rounded) + ws init; blocks 0..15 also do focal+KD ----
__global__ __launch_bounds__(256) void prep_kernel(const float* __restrict__ feat,
                                                   const float* __restrict__ logits,
                                                   const int* __restrict__ labels,
                                                   const float* __restrict__ soft,
                                                   short* __restrict__ featbf,
                                                   float* __restrict__ sqn,
                                                   unsigned* __restrict__ posmax,
                                                   float* __restrict__ negminf,
                                                   float* __restrict__ fpart,
                                                   float* __restrict__ kpart) {
    const int bid = blockIdx.x, tid = threadIdx.x;
    const int wave = tid >> 6, lane = tid & 63;
    const int row = bid * 4 + wave;

    const float* p = feat + (size_t)row * D_FEAT + lane * 8;
    float4 a = *(const float4*)p;
    float4 b = *(const float4*)(p + 4);
    float vals[8] = {a.x, a.y, a.z, a.w, b.x, b.y, b.z, b.w};
    short outv[8];
    float s = 0.f;
#pragma unroll
    for (int j = 0; j < 8; ++j) {
        __hip_bfloat16 h = __float2bfloat16(vals[j]);
        outv[j] = *(short*)&h;
        float xb = __bfloat162float(h);
        s = fmaf(xb, xb, s);
    }
    *(s16x8*)(featbf + (size_t)row * D_FEAT + lane * 8) = *(s16x8*)outv;
    s = waveReduceSum(s);
    if (lane == 0) sqn[row] = s;

    if (tid < 4) posmax[bid * 4 + tid] = 0u;
    else if (tid < 8) negminf[bid * 4 + tid - 4] = 1e12f;

    if (bid < 16) {
        int i = bid * 256 + tid;
        float l0 = logits[2 * i], l1 = logits[2 * i + 1];

        float m = fmaxf(l0, l1);
        float lse = m + logf(expf(l0 - m) + expf(l1 - m));
        float lp = (labels[i] ? l1 : l0) - lse;
        float ce = -lp;
        float pt = expf(lp);
        float om = 1.f - pt;
        float focal = om * om * ce;

        const float Tinv = 1.f / 3.f;
        float s0 = l0 * Tinv, s1 = l1 * Tinv;
        float ms = fmaxf(s0, s1);
        float lses = ms + logf(expf(s0 - ms) + expf(s1 - ms));
        float sl0 = s0 - lses, sl1 = s1 - lses;
        float t0 = logf(soft[2 * i] + 1e-8f) * Tinv;
        float t1 = logf(soft[2 * i + 1] + 1e-8f) * Tinv;
        float mt = fmaxf(t0, t1);
        float lset = mt + logf(expf(t0 - mt) + expf(t1 - mt));
        float tl0 = t0 - lset, tl1 = t1 - lset;
        float p0 = expf(tl0), p1 = expf(tl1);
        float kd = p0 * (tl0 - sl0) + p1 * (tl1 - sl1);

        float fs = waveReduceSum(focal);
        float ks = waveReduceSum(kd);
        __shared__ float sf[4], sk[4];
        if (lane == 0) { sf[wave] = fs; sk[wave] = ks; }
        __syncthreads();
        if (tid == 0) {
            fpart[bid] = sf[0] + sf[1] + sf[2] + sf[3];
            kpart[bid] = sk[0] + sk[1] + sk[2] + sk[3];
        }
    }
}

// ---- pairwise d^2, 256x256 tile, 8 waves (2Mx4N), BK=64, 8-phase (4/K-tile)
// counted-vmcnt schedule (T3+T4) + setprio (T5).
// LDS per buffer: [ks(2)][row(256)][c4(4) x 16B], swizzle c4' = c4 ^ ((row>>1)&3)
// -> gload_lds dest stays linear per wave (64 lanes = 16 rows x 4 slots),
//    ds_read_b128 spreads 8 distinct bank-phases per 8 lanes = 2-way (free).
// Chunks/K-tile (each = 1 gload_lds per wave x 8 waves = 8KB):
//   a0: A rows{0-63,128-191} ks0   a1: A rows{64-127,192-255} ks0   a2,a3: same ks1
//   b0: B rows 0-127 ks0           b1: B rows 128-255 ks0           b2,b3: same ks1
// Phase needs: P1(m0-3,ks0): a0,b0,b1  P2(m4-7,ks0): a1  P3(m0-3,ks1): a2,b2,b3  P4: a3
// Issues (tile t+1): P1: a0,b0  P2: b1,a1  P3: a2,b2  P4: b3,a3
// Ledger (vmcnt at phase end certifies NEXT phase; wait precedes a barrier so
// ALL waves' parts are landed): prologue vmcnt(5); main loop 6,5,6,5; tail 4,1,0,-.
__global__ __launch_bounds__(512) void pairwise_8ph_kernel(const short* __restrict__ featbf,
                                                           const float* __restrict__ sqn,
                                                           const int* __restrict__ labels,
                                                           unsigned* __restrict__ posmax,
                                                           unsigned* __restrict__ negmin) {
    __shared__ short As0[256 * 64], As1[256 * 64];
    __shared__ short Bs0[256 * 64], Bs1[256 * 64];
    const int tid = threadIdx.x;
    const int bfl = blockIdx.x;
    const int xcd = bfl & 7, loc = bfl >> 3;
    const int ib = (xcd & 3) * 4 + (loc & 3);
    const int jb = ((xcd >> 1) & 2) * 4 + (loc >> 2);
    const int wid = tid >> 6, lane = tid & 63;
    const int wr = wid >> 2, wc = wid & 3;
    const int lo = lane & 15, hi = lane >> 4;

    // ---- staging addressing ----
    const int rbA0 = (wid < 4) ? wid * 16 : 64 + wid * 16;  // a0 row-base per wave
    const int rbB0 = wid * 16;                              // b0 row-base
    const int rA0 = rbA0 + (lane >> 2), rA1 = rA0 + 64;
    const int rB0 = rbB0 + (lane >> 2), rB1 = rB0 + 128;
    const int cA0 = (lane & 3) ^ ((rA0 >> 1) & 3), cA1 = (lane & 3) ^ ((rA1 >> 1) & 3);
    const int cB0 = (lane & 3) ^ ((rB0 >> 1) & 3), cB1 = (lane & 3) ^ ((rB1 >> 1) & 3);
    const short* gA0 = featbf + (size_t)(ib * 256 + rA0) * D_FEAT + cA0 * 8;
    const short* gA1 = featbf + (size_t)(ib * 256 + rA1) * D_FEAT + cA1 * 8;
    const short* gB0 = featbf + (size_t)(jb * 256 + rB0) * D_FEAT + cB0 * 8;
    const short* gB1 = featbf + (size_t)(jb * 256 + rB1) * D_FEAT + cB1 * 8;
    const int dA0 = rbA0 * 32, dA1 = (rbA0 + 64) * 32;   // LDS short-offsets (+ks*8192)
    const int dB0 = rbB0 * 32, dB1 = (rbB0 + 128) * 32;

// ISSUE(gptr, buf, dstbase, ks, kt): one chunk (per-wave 1KB; block-wide 8KB)
#define ISSUE(gptr, buf, dstbase, ksv, ktv)                                            \
    GLOAD_LDS16((gptr) + (ktv) * 64 + (ksv) * 32, (buf) + (ksv) * 8192 + (dstbase))

    // ---- fragment ds_read offsets (shorts; + ks*8192) ----
    int aoffs[8], boffs[4];
#pragma unroll
    for (int m = 0; m < 8; ++m) {
        int r = wr * 128 + m * 16 + lo;
        aoffs[m] = r * 32 + ((hi ^ ((r >> 1) & 3)) * 8);
    }
#pragma unroll
    for (int n = 0; n < 4; ++n) {
        int r = wc * 64 + n * 16 + lo;
        boffs[n] = r * 32 + ((hi ^ ((r >> 1) & 3)) * 8);
    }

    f32x4 acc[8][4];
#pragma unroll
    for (int m = 0; m < 8; ++m)
#pragma unroll
        for (int n = 0; n < 4; ++n)
            acc[m][n] = (f32x4){0.f, 0.f, 0.f, 0.f};

#define PHASE(mh, ksv, DO_BFR, ISSUES, VMCNT)                                          \
    {                                                                                  \
        if (DO_BFR) {                                                                  \
            _Pragma("unroll") for (int n = 0; n < 4; ++n)                              \
                bfr[n] = *(const s16x8*)(Bcur + (ksv) * 8192 + boffs[n]);              \
        }                                                                              \
        s16x8 af[4];                                                                   \
        _Pragma("unroll") for (int mi = 0; mi < 4; ++mi)                               \
            af[mi] = *(const s16x8*)(Acur + (ksv) * 8192 + aoffs[(mh) * 4 + mi]);      \
        ISSUES;                                                                        \
        __builtin_amdgcn_s_barrier();                                                  \
        __builtin_amdgcn_sched_barrier(0);                                             \
        __builtin_amdgcn_s_setprio(1);                                                 \
        _Pragma("unroll") for (int mi = 0; mi < 4; ++mi)                               \
            _Pragma("unroll") for (int n = 0; n < 4; ++n)                              \
                acc[(mh) * 4 + mi][n] = __builtin_amdgcn_mfma_f32_16x16x32_bf16(       \
                    af[mi], bfr[n], acc[(mh) * 4 + mi][n], 0, 0, 0);                   \
        __builtin_amdgcn_s_setprio(0);                                                 \
        VMCNT;                                                                         \
        __builtin_amdgcn_s_barrier();                                                  \
        __builtin_amdgcn_sched_barrier(0);                                             \
    }

#define VM(n) asm volatile("s_waitcnt vmcnt(" #n ")" ::: "memory")

    const short* Acur = As0;
    const short* Bcur = Bs0;
    short* Anxt = As1;
    short* Bnxt = Bs1;

    // prologue: tile 0 chunks in ledger order a0,b0,b1,a1,a2,b2,b3,a3
    ISSUE(gA0, As0, dA0, 0, 0);
    ISSUE(gB0, Bs0, dB0, 0, 0);
    ISSUE(gB1, Bs0, dB1, 0, 0);
    ISSUE(gA1, As0, dA1, 0, 0);
    ISSUE(gA0, As0, dA0, 1, 0);
    ISSUE(gB0, Bs0, dB0, 1, 0);
    ISSUE(gB1, Bs0, dB1, 1, 0);
    ISSUE(gA1, As0, dA1, 1, 0);
    VM(5);  // a0,b0,b1 landed (all waves certify at next barrier)
    __builtin_amdgcn_s_barrier();
    __builtin_amdgcn_sched_barrier(0);

#pragma unroll 1
    for (int kt = 0; kt < D_FEAT / 64 - 1; ++kt) {
        s16x8 bfr[4];
        PHASE(0, 0, true,
              { ISSUE(gA0, Anxt, dA0, 0, kt + 1); ISSUE(gB0, Bnxt, dB0, 0, kt + 1); },
              VM(6));
        PHASE(1, 0, false,
              { ISSUE(gB1, Bnxt, dB1, 0, kt + 1); ISSUE(gA1, Anxt, dA1, 0, kt + 1); },
              VM(5));
        PHASE(0, 1, true,
              { ISSUE(gA0, Anxt, dA0, 1, kt + 1); ISSUE(gB0, Bnxt, dB0, 1, kt + 1); },
              VM(6));
        PHASE(1, 1, false,
              { ISSUE(gB1, Bnxt, dB1, 1, kt + 1); ISSUE(gA1, Anxt, dA1, 1, kt + 1); },
              VM(5));
        const short* t1 = Acur; Acur = Anxt; Anxt = (short*)t1;
        const short* t2 = Bcur; Bcur = Bnxt; Bnxt = (short*)t2;
    }
    {  // tail tile (no issues; drain)
        s16x8 bfr[4];
        PHASE(0, 0, true,  {}, VM(4));
        PHASE(1, 0, false, {}, VM(1));
        PHASE(0, 1, true,  {}, VM(0));
        PHASE(1, 1, false, {}, {});
    }

#undef PHASE
#undef VM
#undef ISSUE

    // ---- epilogue in d^2 domain (C/D layout m89: col = lo, row = hi*4 + reg) ----
    int coln[4], labc[4];
    float sqc[4];
#pragma unroll
    for (int n = 0; n < 4; ++n) {
        coln[n] = jb * 256 + wc * 64 + n * 16 + lo;
        labc[n] = labels[coln[n]];
        sqc[n] = sqn[coln[n]];
    }
    __syncthreads();  // K-loop fully done before LDS reuse (tail used As1/Bs1; safe anyway)
    float (*redp)[5] = (float(*)[5])As0;          // [256][5]
    float (*redn)[5] = ((float(*)[5])As0) + 256;  // [256][5]

#pragma unroll
    for (int m = 0; m < 8; ++m) {
#pragma unroll
        for (int r = 0; r < 4; ++r) {
            int row_loc = wr * 128 + m * 16 + hi * 4 + r;
            int row_g = ib * 256 + row_loc;
            int labr = labels[row_g];
            float sqr = sqn[row_g];
            float pm = 0.f, nm = 1e12f;
#pragma unroll
            for (int n = 0; n < 4; ++n) {
                float d2 = fmaxf(sqr + fmaf(-2.f, acc[m][n][r], sqc[n]), 0.f);
                bool same = (labr == labc[n]);
                if (same) {
                    if (row_g != coln[n]) pm = fmaxf(pm, d2);
                } else {
                    nm = fminf(nm, d2);
                }
            }
#pragma unroll
            for (int off = 1; off < 16; off <<= 1) {
                pm = fmaxf(pm, __shfl_xor(pm, off));
                nm = fminf(nm, __shfl_xor(nm, off));
            }
            if (lo == 0) {
                redp[row_loc][wc] = pm;
                redn[row_loc][wc] = nm;
            }
        }
    }
    __syncthreads();
    if (tid < 256) {
        float p = fmaxf(fmaxf(redp[tid][0], redp[tid][1]),
                        fmaxf(redp[tid][2], redp[tid][3]));
        atomicMax(&posmax[ib * 256 + tid], __float_as_uint(p));
    } else {
        int row = tid - 256;
        float nn = fminf(fminf(redn[row][0], redn[row][1]),
                         fminf(redn[row][2], redn[row][3]));
        atomicMin(&negmin[ib * 256 + row], __float_as_uint(nn));
    }
}

// ---- final reduction + scalar combine (sqrt deferred to here; float32 outputs) ----
__global__ __launch_bounds__(256) void finalize_kernel(const unsigned* __restrict__ posmax,
                                                       const unsigned* __restrict__ negmin,
                                                       const float* __restrict__ fpart,
                                                       const float* __restrict__ kpart,
                                                       float* __restrict__ out) {
    int tid = threadIdx.x;
    float sum_pr = 0.f, sum_v = 0.f;
    for (int i = tid; i < B_ROWS; i += 256) {
        float p2 = __uint_as_float(posmax[i]);
        float n2 = __uint_as_float(negmin[i]);
        float v = (p2 > 0.f) ? 1.f : 0.f;
        sum_pr += fmaxf(sqrtf(p2) - sqrtf(n2) + 0.3f, 0.f) * v;
        sum_v += v;
    }
    sum_pr = waveReduceSum(sum_pr);
    sum_v = waveReduceSum(sum_v);
    __shared__ float sp[4], sv[4];
    int wave = tid >> 6, lane = tid & 63;
    if (lane == 0) { sp[wave] = sum_pr; sv[wave] = sum_v; }
    __syncthreads();
    if (tid == 0) {
        float spr = sp[0] + sp[1] + sp[2] + sp[3];
        float svv = sv[0] + sv[1] + sv[2] + sv[3];
        float fsum = 0.f, ksum = 0.f;
        for (int b = 0; b < 16; ++b) { fsum += fpart[b]; ksum += kpart[b]; }
        float focal = fsum / 4096.f;
        float kd = ksum / 4096.f * 9.f;  // * T^2
        float triplet = (svv > 0.f) ? spr / fmaxf(svv, 1.f) : 0.f;
        float total = focal + 0.5f * triplet + kd;
        out[0] = total;
        out[1] = focal;
        out[2] = triplet;
        out[3] = kd;
    }
}

extern "C" void kernel_launch(void* const* d_in, const int* in_sizes, int n_in,
                              void* d_out, int out_size, void* d_ws, size_t ws_size,
                              hipStream_t stream) {
    const float* logits = (const float*)d_in[0];
    const float* feat   = (const float*)d_in[1];
    const int*   labels = (const int*)d_in[2];
    const float* soft   = (const float*)d_in[3];

    char* ws = (char*)d_ws;
    unsigned* posmax = (unsigned*)ws;                    // 4096 u32 (d^2 bits)
    unsigned* negmin = (unsigned*)(ws + 16384);          // 4096 u32 (d^2 bits)
    float*    sqn    = (float*)(ws + 32768);             // 4096 f32
    float*    fpart  = (float*)(ws + 49152);             // 16 f32
    float*    kpart  = (float*)(ws + 49152 + 256);       // 16 f32
    short*    featbf = (short*)(ws + 65536);             // 4096*512 bf16 = 4 MB

    prep_kernel<<<1024, 256, 0, stream>>>(feat, logits, labels, soft, featbf, sqn,
                                          posmax, (float*)negmin, fpart, kpart);
    pairwise_8ph_kernel<<<256, 512, 0, stream>>>(featbf, sqn, labels, posmax, negmin);
    finalize_kernel<<<1, 256, 0, stream>>>(posmax, negmin, fpart, kpart,
                                           (float*)d_out);
}